// Round 2
// baseline (118.398 us; speedup 1.0000x reference)
//
#include <hip/hip_runtime.h>

// Problem: InteractionNet  B=8, N1=256, N2=256, F=128
// All inputs/outputs fp32 (per reference dtypes).
//
// ws layout (floats): m1/x [2048*128] | Mx2 [2048*128]  = 2 MB total.
// x = relu(m1+m2) is computed in-place over the m1 buffer.

#define FDIM 128
#define N2DIM 256

// ---------------- Kernel 1: m1 = x1 @ W_w^T + W_b ; Mx2 = x2 @ M_w^T + M_b ----
// blocks 0..255 -> m1 rows, 256..511 -> Mx2 rows. 8 rows per block, 128 thr.
__global__ __launch_bounds__(128)
void k_lin(const float* __restrict__ x1,
           const float* __restrict__ x2,
           const float* __restrict__ Ww,
           const float* __restrict__ Wb,
           const float* __restrict__ Mw,
           const float* __restrict__ Mb,
           float* __restrict__ m1, float* __restrict__ mx2)
{
  int blk = blockIdx.x;
  int which = blk >> 8;
  int row0 = (blk & 255) << 3;
  const float* X  = which ? x2 : x1;
  const float* W  = which ? Mw : Ww;
  const float* Bv = which ? Mb : Wb;
  float* out = which ? mx2 : m1;

  __shared__ float xs[8][FDIM];
  int tid = threadIdx.x;  // = output column g
#pragma unroll
  for (int r = 0; r < 8; ++r)
    xs[r][tid] = X[(size_t)(row0 + r) * FDIM + tid];
  __syncthreads();

  const float* wrow = W + (size_t)tid * FDIM;
  float acc[8] = {0.f,0.f,0.f,0.f,0.f,0.f,0.f,0.f};
  for (int k0 = 0; k0 < FDIM; k0 += 4) {
    float4 wv = *(const float4*)(wrow + k0);
#pragma unroll
    for (int r = 0; r < 8; ++r) {
      float4 xv = *(const float4*)(&xs[r][k0]);
      acc[r] += xv.x * wv.x + xv.y * wv.y + xv.z * wv.z + xv.w * wv.w;
    }
  }
  float bv = Bv[tid];
#pragma unroll
  for (int r = 0; r < 8; ++r)
    out[(size_t)(row0 + r) * FDIM + tid] = acc[r] + bv;
}

// ---------------- Kernel 2: m2 = max_j(Mx2[b,j,:] * mask[b,i,j]); x = relu(m1+m2)
// One block per (b,i). Compact valid-j list (mask is exactly 0.0/1.0 so the
// product equals the value; any zero mask contributes a 0 term to the max).
// Writes x in-place over the m1 buffer.
__global__ __launch_bounds__(128)
void k_maxrelu(const float* __restrict__ ve,
               const float* __restrict__ mx2,
               float* __restrict__ m1x)
{
  int blk = blockIdx.x;       // b*256 + i
  int b = blk >> 8;
  __shared__ int idx[N2DIM];
  __shared__ int cnt;
  __shared__ int nz;
  int tid = threadIdx.x;
  if (tid == 0) { cnt = 0; nz = 0; }
  __syncthreads();
  const float* e = ve + (size_t)blk * N2DIM;
  for (int j = tid; j < N2DIM; j += 128) {
    float v = e[j];
    if (v != 0.0f) { int p = atomicAdd(&cnt, 1); idx[p] = j; }
    else nz = 1;
  }
  __syncthreads();
  int n = cnt;
  const float* Mbase = mx2 + (size_t)b * N2DIM * FDIM;
  float m2 = nz ? 0.0f : -3.0e38f;
  int i = 0;
  for (; i + 4 <= n; i += 4) {
    float v0 = Mbase[(size_t)idx[i]     * FDIM + tid];
    float v1 = Mbase[(size_t)idx[i + 1] * FDIM + tid];
    float v2 = Mbase[(size_t)idx[i + 2] * FDIM + tid];
    float v3 = Mbase[(size_t)idx[i + 3] * FDIM + tid];
    m2 = fmaxf(m2, fmaxf(fmaxf(v0, v1), fmaxf(v2, v3)));
  }
  for (; i < n; ++i)
    m2 = fmaxf(m2, Mbase[(size_t)idx[i] * FDIM + tid]);
  size_t o = (size_t)blk * FDIM + tid;
  float s = m1x[o] + m2;
  m1x[o] = fmaxf(s, 0.0f);    // in-place: same thread read->write, no hazard
}

// ---------------- Kernel 3: GRUCell(input=x, hidden=x1) --------------------
// 8 rows per block, 256 threads: io=0 half computes gi (vs x), io=1 half gh
// (vs x1); gh exchanged through LDS; io=0 does gates + store.
__global__ __launch_bounds__(256)
void k_gru(const float* __restrict__ xw,
           const float* __restrict__ x1,
           const float* __restrict__ wih,
           const float* __restrict__ whh,
           const float* __restrict__ bih,
           const float* __restrict__ bhh,
           float* __restrict__ out)
{
  int row0 = blockIdx.x << 3;
  int tid = threadIdx.x;
  int f = tid & 127;
  int io = tid >> 7;

  __shared__ float tiles[2][8][FDIM];   // [0]=x (gru input), [1]=x1 (hidden)
  __shared__ float gh_sh[3][8][FDIM];

  for (int t = tid; t < 8 * FDIM; t += 256) {
    int r = t >> 7, c = t & 127;
    tiles[0][r][c] = xw[(size_t)(row0 + r) * FDIM + c];
    tiles[1][r][c] = x1[(size_t)(row0 + r) * FDIM + c];
  }
  __syncthreads();

  const float* Wm = io ? whh : wih;
  const float (*tile)[FDIM] = tiles[io];
  const float* w0p = Wm + (size_t)f * FDIM;
  const float* w1p = Wm + (size_t)(128 + f) * FDIM;
  const float* w2p = Wm + (size_t)(256 + f) * FDIM;

  float a0[8], a1[8], a2[8];
#pragma unroll
  for (int r = 0; r < 8; ++r) { a0[r] = 0.f; a1[r] = 0.f; a2[r] = 0.f; }

  for (int k0 = 0; k0 < FDIM; k0 += 4) {
    float4 c0 = *(const float4*)(w0p + k0);
    float4 c1 = *(const float4*)(w1p + k0);
    float4 c2 = *(const float4*)(w2p + k0);
#pragma unroll
    for (int r = 0; r < 8; ++r) {
      float4 tv = *(const float4*)(&tile[r][k0]);
      a0[r] += tv.x * c0.x + tv.y * c0.y + tv.z * c0.z + tv.w * c0.w;
      a1[r] += tv.x * c1.x + tv.y * c1.y + tv.z * c1.z + tv.w * c1.w;
      a2[r] += tv.x * c2.x + tv.y * c2.y + tv.z * c2.z + tv.w * c2.w;
    }
  }

  const float* Bv = io ? bhh : bih;
  float b0 = Bv[f], b1 = Bv[128 + f], b2 = Bv[256 + f];

  if (io) {
#pragma unroll
    for (int r = 0; r < 8; ++r) {
      gh_sh[0][r][f] = a0[r] + b0;
      gh_sh[1][r][f] = a1[r] + b1;
      gh_sh[2][r][f] = a2[r] + b2;
    }
  }
  __syncthreads();
  if (!io) {
#pragma unroll
    for (int r = 0; r < 8; ++r) {
      float ir  = a0[r] + b0, iz = a1[r] + b1, in_ = a2[r] + b2;
      float hr  = gh_sh[0][r][f];
      float hz  = gh_sh[1][r][f];
      float hn  = gh_sh[2][r][f];
      float rg  = 1.f / (1.f + __expf(-(ir + hr)));
      float zg  = 1.f / (1.f + __expf(-(iz + hz)));
      float pre = in_ + rg * hn;
      float e2  = __expf(2.f * pre);
      float nn  = 1.f - 2.f / (e2 + 1.f);   // tanh(pre)
      float h   = (1.f - zg) * nn + zg * tiles[1][r][f];
      out[(size_t)(row0 + r) * FDIM + f] = h;
    }
  }
}

extern "C" void kernel_launch(void* const* d_in, const int* in_sizes, int n_in,
                              void* d_out, int out_size, void* d_ws, size_t ws_size,
                              hipStream_t stream) {
  (void)in_sizes; (void)n_in; (void)out_size; (void)ws_size;
  const float* x1  = (const float*)d_in[0];
  const float* x2  = (const float*)d_in[1];
  const float* ve  = (const float*)d_in[2];
  const float* Ww  = (const float*)d_in[3];
  const float* Wb  = (const float*)d_in[4];
  const float* Mw  = (const float*)d_in[5];
  const float* Mb  = (const float*)d_in[6];
  const float* wih = (const float*)d_in[7];
  const float* whh = (const float*)d_in[8];
  const float* bih = (const float*)d_in[9];
  const float* bhh = (const float*)d_in[10];
  float* out = (float*)d_out;

  float* ws  = (float*)d_ws;
  float* m1x = ws;               // 262144 floats; becomes x after k_maxrelu
  float* mx2 = ws + 262144;      // 262144 floats

  hipLaunchKernelGGL(k_lin,     dim3(512),  dim3(128), 0, stream,
                     x1, x2, Ww, Wb, Mw, Mb, m1x, mx2);
  hipLaunchKernelGGL(k_maxrelu, dim3(2048), dim3(128), 0, stream,
                     ve, mx2, m1x);
  hipLaunchKernelGGL(k_gru,     dim3(256),  dim3(256), 0, stream,
                     m1x, x1, wih, whh, bih, bhh, out);
}

// Round 3
// 117.765 us; speedup vs baseline: 1.0054x; 1.0054x over previous
//
#include <hip/hip_runtime.h>

// Problem: InteractionNet  B=8, N1=256, N2=256, F=128
// All inputs/outputs fp32 (per reference dtypes).
//
// ws layout (floats): m1/x [2048*128] | Mx2 [2048*128]  = 2 MB total.
// x = relu(m1+m2) is computed in-place over the m1 buffer.
//
// Occupancy notes (R2->R3): all GEMM-ish kernels restructured to >=2
// waves/SIMD so VALU issue and LDS/VMEM issue overlap across waves
// (1 wave/SIMD serializes the issue slots -> ~2x loss).

#define FDIM 128
#define N2DIM 256

// ---------------- Kernel 1: m1 = x1 @ W_w^T + W_b ; Mx2 = x2 @ M_w^T + M_b ----
// 4 rows per block, 128 thr; blocks 0..511 -> m1, 512..1023 -> Mx2.
// 1024 blocks = 4 blocks/CU = 8 waves/CU = 2 waves/SIMD.
__global__ __launch_bounds__(128)
void k_lin(const float* __restrict__ x1,
           const float* __restrict__ x2,
           const float* __restrict__ Ww,
           const float* __restrict__ Wb,
           const float* __restrict__ Mw,
           const float* __restrict__ Mb,
           float* __restrict__ m1, float* __restrict__ mx2)
{
  int blk = blockIdx.x;
  int which = blk >> 9;
  int row0 = (blk & 511) << 2;
  const float* X  = which ? x2 : x1;
  const float* W  = which ? Mw : Ww;
  const float* Bv = which ? Mb : Wb;
  float* out = which ? mx2 : m1;

  __shared__ float xs[4][FDIM];
  int tid = threadIdx.x;  // = output column g
#pragma unroll
  for (int r = 0; r < 4; ++r)
    xs[r][tid] = X[(size_t)(row0 + r) * FDIM + tid];
  __syncthreads();

  const float* wrow = W + (size_t)tid * FDIM;
  float acc[4] = {0.f,0.f,0.f,0.f};
  for (int k0 = 0; k0 < FDIM; k0 += 4) {
    float4 wv = *(const float4*)(wrow + k0);
#pragma unroll
    for (int r = 0; r < 4; ++r) {
      float4 xv = *(const float4*)(&xs[r][k0]);   // LDS broadcast, conflict-free
      acc[r] += xv.x * wv.x + xv.y * wv.y + xv.z * wv.z + xv.w * wv.w;
    }
  }
  float bv = Bv[tid];
#pragma unroll
  for (int r = 0; r < 4; ++r)
    out[(size_t)(row0 + r) * FDIM + tid] = acc[r] + bv;
}

// ---------------- Kernel 2: m2 = max_j(Mx2[b,j,:] * mask[b,i,j]); x = relu(m1+m2)
// One block per (b,i); 2048 blocks = 8 blocks/CU (good L2-latency hiding).
// Mask is exactly 0.0/1.0 so product==value for valid j; any zero mask
// contributes a 0 term to the max. Writes x in-place over m1.
__global__ __launch_bounds__(128)
void k_maxrelu(const float* __restrict__ ve,
               const float* __restrict__ mx2,
               float* __restrict__ m1x)
{
  int blk = blockIdx.x;       // b*256 + i
  int b = blk >> 8;
  __shared__ int idx[N2DIM];
  __shared__ int cnt;
  __shared__ int nz;
  int tid = threadIdx.x;
  if (tid == 0) { cnt = 0; nz = 0; }
  __syncthreads();
  const float* e = ve + (size_t)blk * N2DIM;
  for (int j = tid; j < N2DIM; j += 128) {
    float v = e[j];
    if (v != 0.0f) { int p = atomicAdd(&cnt, 1); idx[p] = j; }
    else nz = 1;
  }
  __syncthreads();
  int n = cnt;
  const float* Mbase = mx2 + (size_t)b * N2DIM * FDIM + tid;
  float m2 = nz ? 0.0f : -3.0e38f;
  int i = 0;
  for (; i + 8 <= n; i += 8) {            // 8 L2 loads in flight
    float v0 = Mbase[(size_t)idx[i]     * FDIM];
    float v1 = Mbase[(size_t)idx[i + 1] * FDIM];
    float v2 = Mbase[(size_t)idx[i + 2] * FDIM];
    float v3 = Mbase[(size_t)idx[i + 3] * FDIM];
    float v4 = Mbase[(size_t)idx[i + 4] * FDIM];
    float v5 = Mbase[(size_t)idx[i + 5] * FDIM];
    float v6 = Mbase[(size_t)idx[i + 6] * FDIM];
    float v7 = Mbase[(size_t)idx[i + 7] * FDIM];
    m2 = fmaxf(m2, fmaxf(fmaxf(fmaxf(v0, v1), fmaxf(v2, v3)),
                         fmaxf(fmaxf(v4, v5), fmaxf(v6, v7))));
  }
  for (; i < n; ++i)
    m2 = fmaxf(m2, Mbase[(size_t)idx[i] * FDIM]);
  size_t o = (size_t)blk * FDIM + tid;
  float s = m1x[o] + m2;
  m1x[o] = fmaxf(s, 0.0f);    // in-place: same thread read->write, no hazard
}

// ---------------- Kernel 3: GRUCell(input=x, hidden=x1) --------------------
// 4 rows per block, 512 blocks = 2 blocks/CU = 2 waves/SIMD.
// io=0 half computes gi (vs x), io=1 half gh (vs x1); gh via LDS.
__global__ __launch_bounds__(256)
void k_gru(const float* __restrict__ xw,
           const float* __restrict__ x1,
           const float* __restrict__ wih,
           const float* __restrict__ whh,
           const float* __restrict__ bih,
           const float* __restrict__ bhh,
           float* __restrict__ out)
{
  int row0 = blockIdx.x << 2;
  int tid = threadIdx.x;
  int f = tid & 127;
  int io = tid >> 7;

  __shared__ float tiles[2][4][FDIM];   // [0]=x (gru input), [1]=x1 (hidden)
  __shared__ float gh_sh[3][4][FDIM];

  for (int t = tid; t < 4 * FDIM; t += 256) {
    int r = t >> 7, c = t & 127;
    tiles[0][r][c] = xw[(size_t)(row0 + r) * FDIM + c];
    tiles[1][r][c] = x1[(size_t)(row0 + r) * FDIM + c];
  }
  __syncthreads();

  const float* Wm = io ? whh : wih;
  const float (*tile)[FDIM] = tiles[io];
  const float* w0p = Wm + (size_t)f * FDIM;
  const float* w1p = Wm + (size_t)(128 + f) * FDIM;
  const float* w2p = Wm + (size_t)(256 + f) * FDIM;

  float a0[4], a1[4], a2[4];
#pragma unroll
  for (int r = 0; r < 4; ++r) { a0[r] = 0.f; a1[r] = 0.f; a2[r] = 0.f; }

  for (int k0 = 0; k0 < FDIM; k0 += 4) {
    float4 c0 = *(const float4*)(w0p + k0);
    float4 c1 = *(const float4*)(w1p + k0);
    float4 c2 = *(const float4*)(w2p + k0);
#pragma unroll
    for (int r = 0; r < 4; ++r) {
      float4 tv = *(const float4*)(&tile[r][k0]);  // LDS broadcast
      a0[r] += tv.x * c0.x + tv.y * c0.y + tv.z * c0.z + tv.w * c0.w;
      a1[r] += tv.x * c1.x + tv.y * c1.y + tv.z * c1.z + tv.w * c1.w;
      a2[r] += tv.x * c2.x + tv.y * c2.y + tv.z * c2.z + tv.w * c2.w;
    }
  }

  const float* Bv = io ? bhh : bih;
  float b0 = Bv[f], b1 = Bv[128 + f], b2 = Bv[256 + f];

  if (io) {
#pragma unroll
    for (int r = 0; r < 4; ++r) {
      gh_sh[0][r][f] = a0[r] + b0;
      gh_sh[1][r][f] = a1[r] + b1;
      gh_sh[2][r][f] = a2[r] + b2;
    }
  }
  __syncthreads();
  if (!io) {
#pragma unroll
    for (int r = 0; r < 4; ++r) {
      float ir  = a0[r] + b0, iz = a1[r] + b1, in_ = a2[r] + b2;
      float hr  = gh_sh[0][r][f];
      float hz  = gh_sh[1][r][f];
      float hn  = gh_sh[2][r][f];
      float rg  = 1.f / (1.f + __expf(-(ir + hr)));
      float zg  = 1.f / (1.f + __expf(-(iz + hz)));
      float pre = in_ + rg * hn;
      float e2  = __expf(2.f * pre);
      float nn  = 1.f - 2.f / (e2 + 1.f);   // tanh(pre)
      float h   = (1.f - zg) * nn + zg * tiles[1][r][f];
      out[(size_t)(row0 + r) * FDIM + f] = h;
    }
  }
}

extern "C" void kernel_launch(void* const* d_in, const int* in_sizes, int n_in,
                              void* d_out, int out_size, void* d_ws, size_t ws_size,
                              hipStream_t stream) {
  (void)in_sizes; (void)n_in; (void)out_size; (void)ws_size;
  const float* x1  = (const float*)d_in[0];
  const float* x2  = (const float*)d_in[1];
  const float* ve  = (const float*)d_in[2];
  const float* Ww  = (const float*)d_in[3];
  const float* Wb  = (const float*)d_in[4];
  const float* Mw  = (const float*)d_in[5];
  const float* Mb  = (const float*)d_in[6];
  const float* wih = (const float*)d_in[7];
  const float* whh = (const float*)d_in[8];
  const float* bih = (const float*)d_in[9];
  const float* bhh = (const float*)d_in[10];
  float* out = (float*)d_out;

  float* ws  = (float*)d_ws;
  float* m1x = ws;               // 262144 floats; becomes x after k_maxrelu
  float* mx2 = ws + 262144;      // 262144 floats

  hipLaunchKernelGGL(k_lin,     dim3(1024), dim3(128), 0, stream,
                     x1, x2, Ww, Wb, Mw, Mb, m1x, mx2);
  hipLaunchKernelGGL(k_maxrelu, dim3(2048), dim3(128), 0, stream,
                     ve, mx2, m1x);
  hipLaunchKernelGGL(k_gru,     dim3(512),  dim3(256), 0, stream,
                     m1x, x1, wih, whh, bih, bhh, out);
}

// Round 4
// 117.686 us; speedup vs baseline: 1.0061x; 1.0007x over previous
//
#include <hip/hip_runtime.h>

// Problem: InteractionNet  B=8, N1=256, N2=256, F=128
// All inputs/outputs fp32 (per reference dtypes).
//
// R4: fused maxrelu+GRU (3 kernels -> 2). ws: m1 [2048*128] | Mx2 [2048*128].
// Measurement note: dur_us window includes harness 256MB ws poison fills
// (~3x40.7us); kernel-side total is ~12us of the ~118us window.

#define FDIM 128
#define N2DIM 256

// ---------------- Kernel 1: m1 = x1 @ W_w^T + W_b ; Mx2 = x2 @ M_w^T + M_b ----
// 4 rows per block, 128 thr; blocks 0..511 -> m1, 512..1023 -> Mx2.
// 1024 blocks = 4 blocks/CU = 2 waves/SIMD.
__global__ __launch_bounds__(128)
void k_lin(const float* __restrict__ x1,
           const float* __restrict__ x2,
           const float* __restrict__ Ww,
           const float* __restrict__ Wb,
           const float* __restrict__ Mw,
           const float* __restrict__ Mb,
           float* __restrict__ m1, float* __restrict__ mx2)
{
  int blk = blockIdx.x;
  int which = blk >> 9;
  int row0 = (blk & 511) << 2;
  const float* X  = which ? x2 : x1;
  const float* W  = which ? Mw : Ww;
  const float* Bv = which ? Mb : Wb;
  float* out = which ? mx2 : m1;

  __shared__ float xs[4][FDIM];
  int tid = threadIdx.x;  // = output column g
#pragma unroll
  for (int r = 0; r < 4; ++r)
    xs[r][tid] = X[(size_t)(row0 + r) * FDIM + tid];
  __syncthreads();

  const float* wrow = W + (size_t)tid * FDIM;
  float acc[4] = {0.f,0.f,0.f,0.f};
  for (int k0 = 0; k0 < FDIM; k0 += 4) {
    float4 wv = *(const float4*)(wrow + k0);
#pragma unroll
    for (int r = 0; r < 4; ++r) {
      float4 xv = *(const float4*)(&xs[r][k0]);   // LDS broadcast, conflict-free
      acc[r] += xv.x * wv.x + xv.y * wv.y + xv.z * wv.z + xv.w * wv.w;
    }
  }
  float bv = Bv[tid];
#pragma unroll
  for (int r = 0; r < 4; ++r)
    out[(size_t)(row0 + r) * FDIM + tid] = acc[r] + bv;
}

// ---------------- Kernel 2 (fused): masked-max + relu + GRUCell -------------
// 4 rows (same b) per block, 256 threads, 512 blocks = 2 blocks/CU.
// Phases: [A] preload x1 tile + compact valid-j lists (64 lanes/row)
//         [B] m2 = max over valid j of Mx2[b,j,f]; x = relu(m1+m2) -> LDS
//         [C] GRU: io=0 half gi (vs x), io=1 half gh (vs x1); gates on io=0.
// Mask is exactly 0.0/1.0: product==value for valid j; any zero mask
// contributes a 0 term to the max (nz flag).
__global__ __launch_bounds__(256)
void k_fused(const float* __restrict__ ve,
             const float* __restrict__ mx2,
             const float* __restrict__ m1,
             const float* __restrict__ x1,
             const float* __restrict__ wih,
             const float* __restrict__ whh,
             const float* __restrict__ bih,
             const float* __restrict__ bhh,
             float* __restrict__ out)
{
  int row0 = blockIdx.x << 2;      // 4 consecutive global rows, same b
  int b = row0 >> 8;
  int tid = threadIdx.x;

  __shared__ float x_sh[4][FDIM];        // GRU input x
  __shared__ float h_sh[4][FDIM];        // hidden = x1 rows
  __shared__ float gh_sh[3][4][FDIM];
  __shared__ int idx[4][N2DIM];
  __shared__ int cnt[4];
  __shared__ int nz[4];

  // [A] preload x1 tile (global loads overlap compaction below)
  for (int t = tid; t < 4 * FDIM; t += 256)
    h_sh[t >> 7][t & 127] = x1[(size_t)row0 * FDIM + t];
  if (tid < 4) { cnt[tid] = 0; nz[tid] = 0; }
  __syncthreads();

  {
    int r = tid >> 6, l = tid & 63;      // 64 lanes compact one row's mask
    const float* e = ve + (size_t)(row0 + r) * N2DIM;
#pragma unroll
    for (int j0 = 0; j0 < N2DIM; j0 += 64) {
      float v = e[j0 + l];
      if (v != 0.0f) { int p = atomicAdd(&cnt[r], 1); idx[r][p] = j0 + l; }
      else nz[r] = 1;
    }
  }
  __syncthreads();

  // [B] masked max + relu; thread (half,f) handles rows {half, half+2}
  {
    int half = tid >> 7, f = tid & 127;
    const float* Mbase = mx2 + (size_t)b * N2DIM * FDIM + f;
#pragma unroll
    for (int rr = 0; rr < 2; ++rr) {
      int r = half + (rr << 1);
      int n = cnt[r];
      const int* ix = idx[r];
      float m2 = nz[r] ? 0.0f : -3.0e38f;
      int i = 0;
      for (; i + 8 <= n; i += 8) {       // 8 L2 loads in flight
        float v0 = Mbase[(size_t)ix[i]     * FDIM];
        float v1 = Mbase[(size_t)ix[i + 1] * FDIM];
        float v2 = Mbase[(size_t)ix[i + 2] * FDIM];
        float v3 = Mbase[(size_t)ix[i + 3] * FDIM];
        float v4 = Mbase[(size_t)ix[i + 4] * FDIM];
        float v5 = Mbase[(size_t)ix[i + 5] * FDIM];
        float v6 = Mbase[(size_t)ix[i + 6] * FDIM];
        float v7 = Mbase[(size_t)ix[i + 7] * FDIM];
        m2 = fmaxf(m2, fmaxf(fmaxf(fmaxf(v0, v1), fmaxf(v2, v3)),
                             fmaxf(fmaxf(v4, v5), fmaxf(v6, v7))));
      }
      for (; i < n; ++i)
        m2 = fmaxf(m2, Mbase[(size_t)ix[i] * FDIM]);
      float s = m1[(size_t)(row0 + r) * FDIM + f] + m2;
      x_sh[r][f] = fmaxf(s, 0.0f);
    }
  }
  __syncthreads();

  // [C] GRU
  int f = tid & 127;
  int io = tid >> 7;
  const float* Wm = io ? whh : wih;
  const float (*tile)[FDIM] = io ? h_sh : x_sh;
  const float* w0p = Wm + (size_t)f * FDIM;
  const float* w1p = Wm + (size_t)(128 + f) * FDIM;
  const float* w2p = Wm + (size_t)(256 + f) * FDIM;

  float a0[4], a1[4], a2[4];
#pragma unroll
  for (int r = 0; r < 4; ++r) { a0[r] = 0.f; a1[r] = 0.f; a2[r] = 0.f; }

  for (int k0 = 0; k0 < FDIM; k0 += 4) {
    float4 c0 = *(const float4*)(w0p + k0);
    float4 c1 = *(const float4*)(w1p + k0);
    float4 c2 = *(const float4*)(w2p + k0);
#pragma unroll
    for (int r = 0; r < 4; ++r) {
      float4 tv = *(const float4*)(&tile[r][k0]);  // LDS broadcast
      a0[r] += tv.x * c0.x + tv.y * c0.y + tv.z * c0.z + tv.w * c0.w;
      a1[r] += tv.x * c1.x + tv.y * c1.y + tv.z * c1.z + tv.w * c1.w;
      a2[r] += tv.x * c2.x + tv.y * c2.y + tv.z * c2.z + tv.w * c2.w;
    }
  }

  const float* Bv = io ? bhh : bih;
  float b0 = Bv[f], b1 = Bv[128 + f], b2 = Bv[256 + f];

  if (io) {
#pragma unroll
    for (int r = 0; r < 4; ++r) {
      gh_sh[0][r][f] = a0[r] + b0;
      gh_sh[1][r][f] = a1[r] + b1;
      gh_sh[2][r][f] = a2[r] + b2;
    }
  }
  __syncthreads();
  if (!io) {
#pragma unroll
    for (int r = 0; r < 4; ++r) {
      float ir  = a0[r] + b0, iz = a1[r] + b1, in_ = a2[r] + b2;
      float hr  = gh_sh[0][r][f];
      float hz  = gh_sh[1][r][f];
      float hn  = gh_sh[2][r][f];
      float rg  = 1.f / (1.f + __expf(-(ir + hr)));
      float zg  = 1.f / (1.f + __expf(-(iz + hz)));
      float pre = in_ + rg * hn;
      float e2  = __expf(2.f * pre);
      float nn  = 1.f - 2.f / (e2 + 1.f);   // tanh(pre)
      float h   = (1.f - zg) * nn + zg * h_sh[r][f];
      out[(size_t)(row0 + r) * FDIM + f] = h;
    }
  }
}

extern "C" void kernel_launch(void* const* d_in, const int* in_sizes, int n_in,
                              void* d_out, int out_size, void* d_ws, size_t ws_size,
                              hipStream_t stream) {
  (void)in_sizes; (void)n_in; (void)out_size; (void)ws_size;
  const float* x1  = (const float*)d_in[0];
  const float* x2  = (const float*)d_in[1];
  const float* ve  = (const float*)d_in[2];
  const float* Ww  = (const float*)d_in[3];
  const float* Wb  = (const float*)d_in[4];
  const float* Mw  = (const float*)d_in[5];
  const float* Mb  = (const float*)d_in[6];
  const float* wih = (const float*)d_in[7];
  const float* whh = (const float*)d_in[8];
  const float* bih = (const float*)d_in[9];
  const float* bhh = (const float*)d_in[10];
  float* out = (float*)d_out;

  float* ws  = (float*)d_ws;
  float* m1  = ws;               // 262144 floats
  float* mx2 = ws + 262144;      // 262144 floats

  hipLaunchKernelGGL(k_lin,   dim3(1024), dim3(128), 0, stream,
                     x1, x2, Ww, Wb, Mw, Mb, m1, mx2);
  hipLaunchKernelGGL(k_fused, dim3(512),  dim3(256), 0, stream,
                     ve, mx2, m1, x1, wih, whh, bih, bhh, out);
}